// Round 1
// baseline (1084.359 us; speedup 1.0000x reference)
//
#include <hip/hip_runtime.h>
#include <math.h>

#define D_MODEL 768
#define D_STATE 16
#define D_CONV  4
#define D_INNER 1536
#define BATCH   2
#define SEQ     512
#define M_ROWS  (BATCH * SEQ)      // 1024
#define N_XZ    (2 * D_INNER)      // 3072
#define N_XDBL  (D_INNER + 2 * D_STATE)  // 1568

// ---------------------------------------------------------------------------
// Tiled fp32 GEMM:  C[m,n] = act( sum_k A[m*lda+k] * B[n*ldb+k] + bias[n] )
// Both A and B are K-major ("NT" layout). BM=BN=64, BK=16, 256 threads,
// 4x4 microtile per thread.
// ---------------------------------------------------------------------------
template <int ACT>  // 0 = none, 1 = softplus
__global__ __launch_bounds__(256) void gemm_nt(
    const float* __restrict__ A, int lda,
    const float* __restrict__ B, int ldb,
    float* __restrict__ C, int ldc,
    const float* __restrict__ bias,
    int M, int N, int K)
{
    const int BM = 64, BN = 64, BK = 16;
    __shared__ float As[BK][BM + 4];   // +4 keeps 16B alignment, 2-way bank alias only
    __shared__ float Bs[BK][BN + 4];
    const int bm = blockIdx.y * BM;
    const int bn = blockIdx.x * BN;
    const int tid = threadIdx.x;
    const int tx = tid & 15;
    const int ty = tid >> 4;

    float acc[4][4] = {};

    for (int k0 = 0; k0 < K; k0 += BK) {
        // Stage tiles: thread t loads k-col (t&15), row (t>>4)+16*p
#pragma unroll
        for (int p = 0; p < 4; ++p) {
            int r = (tid >> 4) + p * 16;
            int c = tid & 15;
            int gm = bm + r;
            int gn = bn + r;
            As[c][r] = (gm < M) ? A[(long)gm * lda + k0 + c] : 0.f;
            Bs[c][r] = (gn < N) ? B[(long)gn * ldb + k0 + c] : 0.f;
        }
        __syncthreads();
#pragma unroll
        for (int kk = 0; kk < BK; ++kk) {
            float a[4], b[4];
#pragma unroll
            for (int i = 0; i < 4; ++i) a[i] = As[kk][ty * 4 + i];
#pragma unroll
            for (int j = 0; j < 4; ++j) b[j] = Bs[kk][tx * 4 + j];
#pragma unroll
            for (int i = 0; i < 4; ++i)
#pragma unroll
                for (int j = 0; j < 4; ++j)
                    acc[i][j] = fmaf(a[i], b[j], acc[i][j]);
        }
        __syncthreads();
    }

#pragma unroll
    for (int i = 0; i < 4; ++i) {
        int gm = bm + ty * 4 + i;
        if (gm >= M) continue;
#pragma unroll
        for (int j = 0; j < 4; ++j) {
            int gn = bn + tx * 4 + j;
            if (gn >= N) continue;
            float v = acc[i][j];
            if (bias) v += bias[gn];
            if (ACT == 1) {
                // jax.nn.softplus = logaddexp(x, 0) = max(x,0) + log1p(exp(-|x|))
                v = fmaxf(v, 0.f) + log1pf(expf(-fabsf(v)));
            }
            C[(long)gm * ldc + gn] = v;
        }
    }
}

// ---------------------------------------------------------------------------
// Depthwise causal conv (width 4) + bias + SiLU.
// xz is (M_ROWS, 3072); x_inner = cols [0,1536). Output xconv (M_ROWS,1536).
// ---------------------------------------------------------------------------
__global__ __launch_bounds__(256) void conv_silu_kernel(
    const float* __restrict__ xz,
    const float* __restrict__ conv_w,  // (1536, 4)
    const float* __restrict__ conv_b,  // (1536)
    float* __restrict__ xconv)
{
    int idx = blockIdx.x * blockDim.x + threadIdx.x;
    if (idx >= M_ROWS * D_INNER) return;
    int d = idx % D_INNER;
    int r = idx / D_INNER;   // b*SEQ + l
    int l = r % SEQ;
    float acc = conv_b[d];
#pragma unroll
    for (int k = 0; k < D_CONV; ++k) {
        int ls = l - (D_CONV - 1) + k;
        if (ls >= 0)
            acc = fmaf(conv_w[d * D_CONV + k], xz[(long)(r - (D_CONV - 1 - k)) * N_XZ + d], acc);
    }
    float s = acc / (1.f + expf(-acc));   // silu
    xconv[idx] = s;
}

// ---------------------------------------------------------------------------
// Scan kernel. One block per (b, d). Replicates the reference's up/down-sweep
// DAG exactly, in linear space (all values positive; logaddexp <-> add).
// Fuses: deltaA/deltaB_u construction, scan, Cmat contraction, +xconv*Dp,
// *silu(z). Writes u (M_ROWS, D_INNER).
// ---------------------------------------------------------------------------
__global__ __launch_bounds__(256) void scan_kernel(
    const float* __restrict__ delta,   // (M_ROWS, 1536)
    const float* __restrict__ xconv,   // (M_ROWS, 1536)
    const float* __restrict__ x_dbl,   // (M_ROWS, 1568); cols 1536..1567 = B|C
    const float* __restrict__ xz,      // (M_ROWS, 3072); cols 1536+ = z
    const float* __restrict__ A_log,   // (1536, 16)
    const float* __restrict__ Dp,      // (1536)
    float* __restrict__ u)             // (M_ROWS, 1536)
{
    __shared__ float BC[SEQ][33];      // [l][0..15]=B, [16..31]=C; pad->conflict-free
    __shared__ float drow[SEQ];
    __shared__ float xrow[SEQ];
    __shared__ float yacc[SEQ];
    __shared__ float Cc[SEQ];
    __shared__ float Vv[SEQ];

    const int blk = blockIdx.x;
    const int b = blk / D_INNER;
    const int d = blk % D_INNER;
    const int tid = threadIdx.x;
    const int base = b * SEQ;

    for (int l = tid; l < SEQ; l += 256) {
        drow[l] = delta[(long)(base + l) * D_INNER + d];
        xrow[l] = xconv[(long)(base + l) * D_INNER + d];
        yacc[l] = 0.f;
    }
    for (int idx = tid; idx < SEQ * 32; idx += 256) {
        int l = idx >> 5, j = idx & 31;
        BC[l][j] = x_dbl[(long)(base + l) * N_XDBL + D_INNER + j];
    }
    __syncthreads();

    for (int n = 0; n < D_STATE; ++n) {
        float Adn = -expf(A_log[d * D_STATE + n]);
        for (int l = tid; l < SEQ; l += 256) {
            float dl = drow[l];
            Cc[l] = expf(dl * Adn) + 1e-12f;                       // deltaA + 1e-12
            Vv[l] = fabsf(dl * BC[l][n] * xrow[l]) + 1e-12f;       // |deltaB_u| + 1e-12
        }
        __syncthreads();
        // up-sweep, levels 0..8  (combine: C_r <- C_l*C_r ; V_r <- V_l + C_r*V_r)
        for (int lev = 0; lev < 9; ++lev) {
            int half = 1 << lev;
            int step = half << 1;
            int np = SEQ >> (lev + 1);
            if (tid < np) {
                int r = step - 1 + tid * step;
                int lf = r - half;
                float cr = Cc[r];
                float nc = Cc[lf] * cr;
                float nv = fmaf(cr, Vv[r], Vv[lf]);
                Cc[r] = nc;
                Vv[r] = nv;
            }
            __syncthreads();
        }
        // down-sweep, levels 8..0  (tmp=V_r ; V_r <- V_l + C_r*V_r ; V_l <- tmp)
        for (int lev = 8; lev >= 0; --lev) {
            int half = 1 << lev;
            int step = half << 1;
            int np = SEQ >> (lev + 1);
            if (tid < np) {
                int r = step - 1 + tid * step;
                int lf = r - half;
                float tmp = Vv[r];
                float nr = fmaf(Cc[r], Vv[r], Vv[lf]);
                Vv[r] = nr;
                Vv[lf] = tmp;
            }
            __syncthreads();
        }
        for (int l = tid; l < SEQ; l += 256) {
            yacc[l] = fmaf(Vv[l], BC[l][16 + n], yacc[l]);   // * Cmat
        }
        __syncthreads();
    }

    float Dpd = Dp[d];
    for (int l = tid; l < SEQ; l += 256) {
        float z = xz[(long)(base + l) * N_XZ + D_INNER + d];
        float sz = z / (1.f + expf(-z));                      // silu(z)
        float val = fmaf(xrow[l], Dpd, yacc[l]) * sz;         // (y + xconv*Dp) * silu(z)
        u[(long)(base + l) * D_INNER + d] = val;
    }
}

// ---------------------------------------------------------------------------
extern "C" void kernel_launch(void* const* d_in, const int* in_sizes, int n_in,
                              void* d_out, int out_size, void* d_ws, size_t ws_size,
                              hipStream_t stream)
{
    (void)in_sizes; (void)n_in; (void)out_size; (void)ws_size;

    const float* x      = (const float*)d_in[0];   // (2, 512, 768)
    const float* W_in   = (const float*)d_in[1];   // (3072, 768)
    const float* conv_w = (const float*)d_in[2];   // (1536, 1, 4)
    const float* conv_b = (const float*)d_in[3];   // (1536)
    const float* W_x    = (const float*)d_in[4];   // (1568, 1536)
    const float* W_dt   = (const float*)d_in[5];   // (1536, 1536)
    const float* b_dt   = (const float*)d_in[6];   // (1536)
    const float* A_log  = (const float*)d_in[7];   // (1536, 16)
    const float* Dp     = (const float*)d_in[8];   // (1536)
    const float* W_out  = (const float*)d_in[9];   // (768, 1536)
    float* out = (float*)d_out;                    // (2, 512, 768)

    float* ws = (float*)d_ws;
    float* xz    = ws;                                   // 1024*3072
    float* xconv = xz    + (long)M_ROWS * N_XZ;          // 1024*1536
    float* x_dbl = xconv + (long)M_ROWS * D_INNER;       // 1024*1568
    float* delta = x_dbl + (long)M_ROWS * N_XDBL;        // 1024*1536
    float* u     = delta + (long)M_ROWS * D_INNER;       // 1024*1536

    dim3 blk(256);

    // 1) xz = x @ W_in.T   (1024x768)x(3072x768)^T
    {
        dim3 grid((N_XZ + 63) / 64, (M_ROWS + 63) / 64);
        hipLaunchKernelGGL((gemm_nt<0>), grid, blk, 0, stream,
                           x, D_MODEL, W_in, D_MODEL, xz, N_XZ, nullptr,
                           M_ROWS, N_XZ, D_MODEL);
    }
    // 2) depthwise conv + bias + silu -> xconv
    {
        dim3 grid((M_ROWS * D_INNER + 255) / 256);
        hipLaunchKernelGGL(conv_silu_kernel, grid, blk, 0, stream,
                           xz, conv_w, conv_b, xconv);
    }
    // 3) x_dbl = xconv @ W_x.T   (1024x1536)x(1568x1536)^T
    {
        dim3 grid((N_XDBL + 63) / 64, (M_ROWS + 63) / 64);
        hipLaunchKernelGGL((gemm_nt<0>), grid, blk, 0, stream,
                           xconv, D_INNER, W_x, D_INNER, x_dbl, N_XDBL, nullptr,
                           M_ROWS, N_XDBL, D_INNER);
    }
    // 4) delta = softplus(x_dbl[:, :1536] @ W_dt.T + b_dt)
    {
        dim3 grid((D_INNER + 63) / 64, (M_ROWS + 63) / 64);
        hipLaunchKernelGGL((gemm_nt<1>), grid, blk, 0, stream,
                           x_dbl, N_XDBL, W_dt, D_INNER, delta, D_INNER, b_dt,
                           M_ROWS, D_INNER, D_INNER);
    }
    // 5) scan + gating -> u
    {
        dim3 grid(BATCH * D_INNER);
        hipLaunchKernelGGL(scan_kernel, grid, blk, 0, stream,
                           delta, xconv, x_dbl, xz, A_log, Dp, u);
    }
    // 6) out = u @ W_out.T   (1024x1536)x(768x1536)^T
    {
        dim3 grid((D_MODEL + 63) / 64, (M_ROWS + 63) / 64);
        hipLaunchKernelGGL((gemm_nt<0>), grid, blk, 0, stream,
                           u, D_INNER, W_out, D_INNER, out, D_MODEL, nullptr,
                           M_ROWS, D_MODEL, D_INNER);
    }
}

// Round 2
// 875.610 us; speedup vs baseline: 1.2384x; 1.2384x over previous
//
#include <hip/hip_runtime.h>
#include <math.h>

#define D_MODEL 768
#define D_STATE 16
#define D_CONV  4
#define D_INNER 1536
#define BATCH   2
#define SEQ     512
#define M_ROWS  (BATCH * SEQ)            // 1024
#define N_XZ    (2 * D_INNER)            // 3072
#define N_XDBL  (D_INNER + 2 * D_STATE)  // 1568

// ---------------------------------------------------------------------------
// Tiled fp32 GEMM:  C = act( A @ B^T + bias )
//   TRA=false: A is row-major (M,K), lda = row stride (K-ish)
//   TRA=true : A is transposed (K,M), lda = row stride (=M total)
//   TRC=false: C[m*ldc+n]   TRC=true: C[n*ldc+m]
// B always (N,K) row-major. BM=BN=64, BK=16, 256 threads, 4x4 microtile.
// ---------------------------------------------------------------------------
template <int ACT, bool TRA, bool TRC>  // ACT: 0 none, 1 softplus
__global__ __launch_bounds__(256) void gemm_nt(
    const float* __restrict__ A, int lda,
    const float* __restrict__ B, int ldb,
    float* __restrict__ C, int ldc,
    const float* __restrict__ bias,
    int M, int N, int K)
{
    const int BM = 64, BN = 64, BK = 16;
    __shared__ float As[BK][BM + 4];
    __shared__ float Bs[BK][BN + 4];
    const int bm = blockIdx.y * BM;
    const int bn = blockIdx.x * BN;
    const int tid = threadIdx.x;
    const int tx = tid & 15;
    const int ty = tid >> 4;

    float acc[4][4] = {};

    for (int k0 = 0; k0 < K; k0 += BK) {
        if (TRA) {
            // A is (K, M): coalesced rows of AT. M assumed multiple of 64 here
            // (both users have M=1024), K multiple of 16.
            int c2 = (tid >> 6) * 4;
            int r2 = tid & 63;
#pragma unroll
            for (int q = 0; q < 4; ++q)
                As[c2 + q][r2] = A[(long)(k0 + c2 + q) * lda + bm + r2];
        } else {
#pragma unroll
            for (int p = 0; p < 4; ++p) {
                int r = (tid >> 4) + p * 16;
                int c = tid & 15;
                int gm = bm + r;
                As[c][r] = (gm < M) ? A[(long)gm * lda + k0 + c] : 0.f;
            }
        }
#pragma unroll
        for (int p = 0; p < 4; ++p) {
            int r = (tid >> 4) + p * 16;
            int c = tid & 15;
            int gn = bn + r;
            Bs[c][r] = (gn < N) ? B[(long)gn * ldb + k0 + c] : 0.f;
        }
        __syncthreads();
#pragma unroll
        for (int kk = 0; kk < BK; ++kk) {
            float a[4], b[4];
#pragma unroll
            for (int i = 0; i < 4; ++i) a[i] = As[kk][ty * 4 + i];
#pragma unroll
            for (int j = 0; j < 4; ++j) b[j] = Bs[kk][tx * 4 + j];
#pragma unroll
            for (int i = 0; i < 4; ++i)
#pragma unroll
                for (int j = 0; j < 4; ++j)
                    acc[i][j] = fmaf(a[i], b[j], acc[i][j]);
        }
        __syncthreads();
    }

#pragma unroll
    for (int i = 0; i < 4; ++i) {
        int gm = bm + ty * 4 + i;
        if (gm >= M) continue;
#pragma unroll
        for (int j = 0; j < 4; ++j) {
            int gn = bn + tx * 4 + j;
            if (gn >= N) continue;
            float v = acc[i][j];
            if (bias) v += bias[gn];
            if (ACT == 1) {
                v = fmaxf(v, 0.f) + log1pf(expf(-fabsf(v)));  // softplus
            }
            if (TRC) C[(long)gn * ldc + gm] = v;
            else     C[(long)gm * ldc + gn] = v;
        }
    }
}

// ---------------------------------------------------------------------------
// Depthwise causal conv (width 4) + bias + SiLU -> xconvT (transposed),
// plus zsiluT = silu(z) (transposed). Reads xz row-major (coalesced: d fastest).
// ---------------------------------------------------------------------------
__global__ __launch_bounds__(256) void conv_silu_kernel(
    const float* __restrict__ xz,
    const float* __restrict__ conv_w,  // (1536, 4)
    const float* __restrict__ conv_b,  // (1536)
    float* __restrict__ xconvT,        // (1536, 1024)
    float* __restrict__ zsiluT)        // (1536, 1024)
{
    int idx = blockIdx.x * blockDim.x + threadIdx.x;
    if (idx >= M_ROWS * D_INNER) return;
    int d = idx % D_INNER;
    int r = idx / D_INNER;   // b*SEQ + l
    int l = r % SEQ;
    float acc = conv_b[d];
#pragma unroll
    for (int k = 0; k < D_CONV; ++k) {
        if (l - (D_CONV - 1) + k >= 0)
            acc = fmaf(conv_w[d * D_CONV + k],
                       xz[(long)(r - (D_CONV - 1 - k)) * N_XZ + d], acc);
    }
    xconvT[(long)d * M_ROWS + r] = acc / (1.f + expf(-acc));
    float z = xz[(long)r * N_XZ + D_INNER + d];
    zsiluT[(long)d * M_ROWS + r] = z / (1.f + expf(-z));
}

// ---------------------------------------------------------------------------
// Wave-per-(b,d) register scan. Lane t owns elements l = 8t..8t+7.
// Blelloch up/down DAG of the reference, in linear space:
//   levels 0..2 in-register within lane; levels 3..8 via shuffles on slot 7.
// Zero barriers in the scan; B staged once per block in swizzled LDS
// (addr = n*577 + l + (l>>3): both write (j varies) and stride-8 read
// (bank = (n+9t+i) mod 32, 9 odd) are 2-way max = free).
// ---------------------------------------------------------------------------
__global__ __launch_bounds__(256) void scan_kernel(
    const float* __restrict__ deltaT,   // (1536, 1024)
    const float* __restrict__ xconvT,   // (1536, 1024)
    const float* __restrict__ zsiluT,   // (1536, 1024)
    const float* __restrict__ x_dbl,    // (1024, 1568); cols 1536..1567 = B|C
    const float* __restrict__ A_log,    // (1536, 16)
    const float* __restrict__ Dp,       // (1536)
    float* __restrict__ uT)             // (1536, 1024)
{
    __shared__ float Bsh[16 * 577];

    const int bid = blockIdx.x;          // 0..767
    const int b   = bid / (D_INNER / 4);
    const int dg  = bid % (D_INNER / 4);
    const int tid = threadIdx.x;
    const int w   = tid >> 6;
    const int t   = tid & 63;
    const int d   = dg * 4 + w;
    const int base = b * SEQ;

    // stage B (x_dbl cols 1536..1551) for this batch, swizzled
    for (int idx = tid; idx < SEQ * 16; idx += 256) {
        int j = idx & 15;
        int l = idx >> 4;
        Bsh[j * 577 + l + (l >> 3)] = x_dbl[(long)(base + l) * N_XDBL + D_INNER + j];
    }
    __syncthreads();

    const int l0 = 8 * t;
    float dl[8], xr[8], yac[8];
#pragma unroll
    for (int i = 0; i < 8; ++i) {
        dl[i] = deltaT[(long)d * M_ROWS + base + l0 + i];
        xr[i] = xconvT[(long)d * M_ROWS + base + l0 + i];
        yac[i] = 0.f;
    }
    const int permBase = 9 * t;   // l0 + (l0>>3)

    for (int n = 0; n < D_STATE; ++n) {
        const float Adn = -expf(A_log[d * D_STATE + n]);
        float c[8], v[8];
#pragma unroll
        for (int i = 0; i < 8; ++i) {
            float Bv = Bsh[n * 577 + permBase + i];
            c[i] = expf(dl[i] * Adn) + 1e-12f;              // deltaA + 1e-12
            v[i] = fabsf(dl[i] * Bv * xr[i]) + 1e-12f;      // |deltaB_u| + 1e-12
        }
        // ---- up-sweep, in-lane levels 0..2 ----
#pragma unroll
        for (int p = 0; p < 8; p += 2) { v[p+1] = fmaf(c[p+1], v[p+1], v[p]); c[p+1] *= c[p]; }
        v[3] = fmaf(c[3], v[3], v[1]); c[3] *= c[1];
        v[7] = fmaf(c[7], v[7], v[5]); c[7] *= c[5];
        v[7] = fmaf(c[7], v[7], v[3]); c[7] *= c[3];
        // ---- up-sweep, cross-lane levels 3..8 (slot 7 only) ----
        float c7 = c[7], v7 = v[7];
#pragma unroll
        for (int h = 1; h <= 32; h <<= 1) {
            float vl = __shfl_up(v7, (unsigned)h);
            float cl = __shfl_up(c7, (unsigned)h);
            bool right = ((t & (2 * h - 1)) == (2 * h - 1));
            if (right) { v7 = fmaf(c7, v7, vl); c7 *= cl; }
        }
        // ---- down-sweep, cross-lane levels 8..3 ----
#pragma unroll
        for (int h = 32; h >= 1; h >>= 1) {
            float vl = __shfl_up(v7, (unsigned)h);
            float vr = __shfl_down(v7, (unsigned)h);
            bool right = ((t & (2 * h - 1)) == (2 * h - 1));
            bool left  = ((t & (2 * h - 1)) == (h - 1));
            float nv = v7;
            if (right) nv = fmaf(c7, v7, vl);
            if (left)  nv = vr;
            v7 = nv;
        }
        v[7] = v7;
        c[7] = c7;   // post-up-sweep coeff, needed by in-lane down levels
        // ---- down-sweep, in-lane levels 2..0 ----
        float tmp;
        tmp = v[7]; v[7] = fmaf(c[7], v[7], v[3]); v[3] = tmp;          // level 2
        tmp = v[3]; v[3] = fmaf(c[3], v[3], v[1]); v[1] = tmp;          // level 1
        tmp = v[7]; v[7] = fmaf(c[7], v[7], v[5]); v[5] = tmp;
#pragma unroll
        for (int p = 0; p < 8; p += 2) {                                 // level 0
            tmp = v[p+1]; v[p+1] = fmaf(c[p+1], v[p+1], v[p]); v[p] = tmp;
        }
        // ---- epilogue: contract with Cmat (L1-resident line per row) ----
#pragma unroll
        for (int i = 0; i < 8; ++i) {
            float Cv = x_dbl[(long)(base + l0 + i) * N_XDBL + D_INNER + D_STATE + n];
            yac[i] = fmaf(v[i], Cv, yac[i]);
        }
    }

    const float Dpd = Dp[d];
#pragma unroll
    for (int i = 0; i < 8; ++i) {
        float uv = fmaf(xr[i], Dpd, yac[i]) * zsiluT[(long)d * M_ROWS + base + l0 + i];
        uT[(long)d * M_ROWS + base + l0 + i] = uv;
    }
}

// ---------------------------------------------------------------------------
extern "C" void kernel_launch(void* const* d_in, const int* in_sizes, int n_in,
                              void* d_out, int out_size, void* d_ws, size_t ws_size,
                              hipStream_t stream)
{
    (void)in_sizes; (void)n_in; (void)out_size; (void)ws_size;

    const float* x      = (const float*)d_in[0];   // (2, 512, 768)
    const float* W_in   = (const float*)d_in[1];   // (3072, 768)
    const float* conv_w = (const float*)d_in[2];   // (1536, 1, 4)
    const float* conv_b = (const float*)d_in[3];   // (1536)
    const float* W_x    = (const float*)d_in[4];   // (1568, 1536)
    const float* W_dt   = (const float*)d_in[5];   // (1536, 1536)
    const float* b_dt   = (const float*)d_in[6];   // (1536)
    const float* A_log  = (const float*)d_in[7];   // (1536, 16)
    const float* Dp     = (const float*)d_in[8];   // (1536)
    const float* W_out  = (const float*)d_in[9];   // (768, 1536)
    float* out = (float*)d_out;                    // (2, 512, 768)

    // Workspace. xz is dead after the conv kernel, so deltaT and uT alias it
    // (each 1536*1024 = half of xz's 1024*3072).
    float* ws     = (float*)d_ws;
    float* xz     = ws;                                        // 1024*3072
    float* deltaT = xz;                                        // 1536*1024 (aliases xz lo)
    float* uT     = xz + (long)D_INNER * M_ROWS;               // 1536*1024 (aliases xz hi)
    float* xconvT = xz + (long)M_ROWS * N_XZ;                  // 1536*1024
    float* zsiluT = xconvT + (long)D_INNER * M_ROWS;           // 1536*1024
    float* x_dbl  = zsiluT + (long)D_INNER * M_ROWS;           // 1024*1568

    dim3 blk(256);

    // 1) xz = x @ W_in.T
    {
        dim3 grid(N_XZ / 64, M_ROWS / 64);
        hipLaunchKernelGGL((gemm_nt<0, false, false>), grid, blk, 0, stream,
                           x, D_MODEL, W_in, D_MODEL, xz, N_XZ, (const float*)nullptr,
                           M_ROWS, N_XZ, D_MODEL);
    }
    // 2) depthwise conv + silu -> xconvT; silu(z) -> zsiluT
    {
        dim3 grid((M_ROWS * D_INNER) / 256);
        hipLaunchKernelGGL(conv_silu_kernel, grid, blk, 0, stream,
                           xz, conv_w, conv_b, xconvT, zsiluT);
    }
    // 3) x_dbl = xconv @ W_x.T   (A transposed in memory)
    {
        dim3 grid((N_XDBL + 63) / 64, M_ROWS / 64);
        hipLaunchKernelGGL((gemm_nt<0, true, false>), grid, blk, 0, stream,
                           xconvT, M_ROWS, W_x, D_INNER, x_dbl, N_XDBL, (const float*)nullptr,
                           M_ROWS, N_XDBL, D_INNER);
    }
    // 4) deltaT = softplus(x_dbl[:, :1536] @ W_dt.T + b_dt), stored transposed
    {
        dim3 grid(D_INNER / 64, M_ROWS / 64);
        hipLaunchKernelGGL((gemm_nt<1, false, true>), grid, blk, 0, stream,
                           x_dbl, N_XDBL, W_dt, D_INNER, deltaT, M_ROWS, b_dt,
                           M_ROWS, D_INNER, D_INNER);
    }
    // 5) scan + gating -> uT
    {
        dim3 grid(BATCH * (D_INNER / 4));
        hipLaunchKernelGGL(scan_kernel, grid, blk, 0, stream,
                           deltaT, xconvT, zsiluT, x_dbl, A_log, Dp, uT);
    }
    // 6) out = u @ W_out.T   (A transposed in memory)
    {
        dim3 grid(D_MODEL / 64, M_ROWS / 64);
        hipLaunchKernelGGL((gemm_nt<0, true, false>), grid, blk, 0, stream,
                           uT, M_ROWS, W_out, D_INNER, out, D_MODEL, (const float*)nullptr,
                           M_ROWS, D_MODEL, D_INNER);
    }
}

// Round 3
// 530.346 us; speedup vs baseline: 2.0446x; 1.6510x over previous
//
#include <hip/hip_runtime.h>
#include <math.h>

#define D_MODEL 768
#define D_STATE 16
#define D_CONV  4
#define D_INNER 1536
#define BATCH   2
#define SEQ     512
#define M_ROWS  (BATCH * SEQ)            // 1024
#define N_XZ    (2 * D_INNER)            // 3072
#define N_XDBL  (D_INNER + 2 * D_STATE)  // 1568

typedef short  short8 __attribute__((ext_vector_type(8)));
typedef float  f32x4  __attribute__((ext_vector_type(4)));
typedef unsigned short ushort_t;

// ---- manual bf16 helpers (RNE), raw ushort storage ----
__device__ __forceinline__ ushort_t f2bf(float f) {
    unsigned int u = __float_as_uint(f);
    return (ushort_t)((u + 0x7fffu + ((u >> 16) & 1u)) >> 16);
}
__device__ __forceinline__ float bf2f(ushort_t s) {
    return __uint_as_float((unsigned int)s << 16);
}
__device__ __forceinline__ void split1(float x, ushort_t& h, ushort_t& l) {
    h = f2bf(x);
    l = f2bf(x - bf2f(h));
}

// ---------------------------------------------------------------------------
// Split fp32 -> (hi, lo) bf16.  n multiple of 1024; 4 elements/thread.
// ---------------------------------------------------------------------------
__global__ __launch_bounds__(256) void split_kernel(
    const float* __restrict__ in, ushort_t* __restrict__ hi,
    ushort_t* __restrict__ lo, int n)
{
    int i = (blockIdx.x * 256 + threadIdx.x) * 4;
    if (i >= n) return;
    float4 v = *(const float4*)(in + i);
    ushort_t h0,h1,h2,h3,l0,l1,l2,l3;
    split1(v.x,h0,l0); split1(v.y,h1,l1); split1(v.z,h2,l2); split1(v.w,h3,l3);
    hi[i+0]=h0; hi[i+1]=h1; hi[i+2]=h2; hi[i+3]=h3;
    lo[i+0]=l0; lo[i+1]=l1; lo[i+2]=l2; lo[i+3]=l3;
}

// ---------------------------------------------------------------------------
// Split-bf16 MFMA GEMM:  C[m,n] = epi( sum_k A[m,k]*B[n,k] )
// A (M,K), B (N,K) given as hi/lo bf16 (raw ushort). 128x128 block tile,
// 4 waves of 64x64, mfma_f32_16x16x32_bf16, 3-product split.
// LDS is laid out in MFMA-fragment order: slot(m,kq) = (m>>4)*64 + kq*16 + (m&15),
// 16 B per slot -> every ds_read_b128 is lane-contiguous (conflict-free).
// EPI: 0 = plain fp32 store; 1 = +bias[row] then softplus; 2 = fp32 + split-bf16 store.
// Requires: M % 128 == 0, K % 32 == 0; N guarded.
// ---------------------------------------------------------------------------
template <int EPI>
__global__ __launch_bounds__(256) void gemm_mfma(
    const ushort_t* __restrict__ Ah, const ushort_t* __restrict__ Al, int lda,
    const ushort_t* __restrict__ Bh, const ushort_t* __restrict__ Bl, int ldb,
    float* __restrict__ C, int ldc,
    ushort_t* __restrict__ Ch, ushort_t* __restrict__ Cl,
    const float* __restrict__ bias,
    int N, int K)
{
    __shared__ short8 lds[4 * 512];          // AH | AL | BH | BL, 8 KB each
    short8* AHs = lds;
    short8* ALs = lds + 512;
    short8* BHs = lds + 1024;
    short8* BLs = lds + 1536;

    const int tid  = threadIdx.x;
    const int w    = tid >> 6;
    const int lane = tid & 63;
    const int bm = blockIdx.y * 128;
    const int bn = blockIdx.x * 128;
    const int wm = (w & 1) * 64;
    const int wn = (w >> 1) * 64;

    f32x4 acc[4][4] = {};

    for (int k0 = 0; k0 < K; k0 += 32) {
#pragma unroll
        for (int rep = 0; rep < 2; ++rep) {
            int idx = rep * 256 + tid;
            int m = idx >> 2, g = idx & 3;
            int slot = (m >> 4) * 64 + g * 16 + (m & 15);
            long aoff = (long)(bm + m) * lda + k0 + g * 8;
            AHs[slot] = *(const short8*)(Ah + aoff);
            ALs[slot] = *(const short8*)(Al + aoff);
            if (bn + m < N) {
                long boff = (long)(bn + m) * ldb + k0 + g * 8;
                BHs[slot] = *(const short8*)(Bh + boff);
                BLs[slot] = *(const short8*)(Bl + boff);
            } else {
                short8 z = {0,0,0,0,0,0,0,0};
                BHs[slot] = z; BLs[slot] = z;
            }
        }
        __syncthreads();

        short8 afh[4], afl[4], bfh[4], bfl[4];
#pragma unroll
        for (int mt = 0; mt < 4; ++mt) {
            int MT = (w & 1) * 4 + mt;
            afh[mt] = AHs[MT * 64 + lane];
            afl[mt] = ALs[MT * 64 + lane];
        }
#pragma unroll
        for (int nt = 0; nt < 4; ++nt) {
            int NT = (w >> 1) * 4 + nt;
            bfh[nt] = BHs[NT * 64 + lane];
            bfl[nt] = BLs[NT * 64 + lane];
        }
#pragma unroll
        for (int mt = 0; mt < 4; ++mt)
#pragma unroll
            for (int nt = 0; nt < 4; ++nt) {
                acc[mt][nt] = __builtin_amdgcn_mfma_f32_16x16x32_bf16(afl[mt], bfh[nt], acc[mt][nt], 0, 0, 0);
                acc[mt][nt] = __builtin_amdgcn_mfma_f32_16x16x32_bf16(afh[mt], bfl[nt], acc[mt][nt], 0, 0, 0);
                acc[mt][nt] = __builtin_amdgcn_mfma_f32_16x16x32_bf16(afh[mt], bfh[nt], acc[mt][nt], 0, 0, 0);
            }
        __syncthreads();
    }

    // epilogue: C/D layout col = lane&15, row = (lane>>4)*4 + reg  [m89/m91]
    const int col0 = lane & 15;
    const int quad = lane >> 4;
#pragma unroll
    for (int mt = 0; mt < 4; ++mt)
#pragma unroll
        for (int nt = 0; nt < 4; ++nt)
#pragma unroll
            for (int r = 0; r < 4; ++r) {
                int row = bm + wm + mt * 16 + quad * 4 + r;
                int col = bn + wn + nt * 16 + col0;
                if (col >= N) continue;
                float v = acc[mt][nt][r];
                if (EPI == 1) {
                    v += bias[row];
                    v = fmaxf(v, 0.f) + log1pf(expf(-fabsf(v)));  // softplus
                }
                C[(long)row * ldc + col] = v;
                if (EPI == 2) {
                    ushort_t h, l;
                    split1(v, h, l);
                    Ch[(long)row * ldc + col] = h;
                    Cl[(long)row * ldc + col] = l;
                }
            }
}

// ---------------------------------------------------------------------------
// Depthwise causal conv (width 4) + bias + SiLU.
// Outputs: xconvT fp32 (1536,1024) for scan; xconv split bf16 (1024,1536)
// for GEMM3; zsiluT fp32 (1536,1024).
// ---------------------------------------------------------------------------
__global__ __launch_bounds__(256) void conv_silu_kernel(
    const float* __restrict__ xz,
    const float* __restrict__ conv_w,
    const float* __restrict__ conv_b,
    float* __restrict__ xconvT,
    float* __restrict__ zsiluT,
    ushort_t* __restrict__ xch,
    ushort_t* __restrict__ xcl)
{
    int idx = blockIdx.x * blockDim.x + threadIdx.x;
    if (idx >= M_ROWS * D_INNER) return;
    int d = idx % D_INNER;
    int r = idx / D_INNER;
    int l = r % SEQ;
    float acc = conv_b[d];
#pragma unroll
    for (int k = 0; k < D_CONV; ++k) {
        if (l - (D_CONV - 1) + k >= 0)
            acc = fmaf(conv_w[d * D_CONV + k],
                       xz[(long)(r - (D_CONV - 1 - k)) * N_XZ + d], acc);
    }
    float s = acc / (1.f + expf(-acc));
    xconvT[(long)d * M_ROWS + r] = s;
    ushort_t h, lo;
    split1(s, h, lo);
    xch[idx] = h;
    xcl[idx] = lo;
    float z = xz[(long)r * N_XZ + D_INNER + d];
    zsiluT[(long)d * M_ROWS + r] = z / (1.f + expf(-z));
}

// ---------------------------------------------------------------------------
// Wave-per-(b,d) register scan (unchanged from R2 — verified).
// ---------------------------------------------------------------------------
__global__ __launch_bounds__(256) void scan_kernel(
    const float* __restrict__ deltaT,
    const float* __restrict__ xconvT,
    const float* __restrict__ zsiluT,
    const float* __restrict__ x_dbl,
    const float* __restrict__ A_log,
    const float* __restrict__ Dp,
    float* __restrict__ uT)
{
    __shared__ float Bsh[16 * 577];

    const int bid = blockIdx.x;
    const int b   = bid / (D_INNER / 4);
    const int dg  = bid % (D_INNER / 4);
    const int tid = threadIdx.x;
    const int w   = tid >> 6;
    const int t   = tid & 63;
    const int d   = dg * 4 + w;
    const int base = b * SEQ;

    for (int idx = tid; idx < SEQ * 16; idx += 256) {
        int j = idx & 15;
        int l = idx >> 4;
        Bsh[j * 577 + l + (l >> 3)] = x_dbl[(long)(base + l) * N_XDBL + D_INNER + j];
    }
    __syncthreads();

    const int l0 = 8 * t;
    float dl[8], xr[8], yac[8];
#pragma unroll
    for (int i = 0; i < 8; ++i) {
        dl[i] = deltaT[(long)d * M_ROWS + base + l0 + i];
        xr[i] = xconvT[(long)d * M_ROWS + base + l0 + i];
        yac[i] = 0.f;
    }
    const int permBase = 9 * t;

    for (int n = 0; n < D_STATE; ++n) {
        const float Adn = -expf(A_log[d * D_STATE + n]);
        float c[8], v[8];
#pragma unroll
        for (int i = 0; i < 8; ++i) {
            float Bv = Bsh[n * 577 + permBase + i];
            c[i] = expf(dl[i] * Adn) + 1e-12f;
            v[i] = fabsf(dl[i] * Bv * xr[i]) + 1e-12f;
        }
#pragma unroll
        for (int p = 0; p < 8; p += 2) { v[p+1] = fmaf(c[p+1], v[p+1], v[p]); c[p+1] *= c[p]; }
        v[3] = fmaf(c[3], v[3], v[1]); c[3] *= c[1];
        v[7] = fmaf(c[7], v[7], v[5]); c[7] *= c[5];
        v[7] = fmaf(c[7], v[7], v[3]); c[7] *= c[3];
        float c7 = c[7], v7 = v[7];
#pragma unroll
        for (int h = 1; h <= 32; h <<= 1) {
            float vl = __shfl_up(v7, (unsigned)h);
            float cl = __shfl_up(c7, (unsigned)h);
            bool right = ((t & (2 * h - 1)) == (2 * h - 1));
            if (right) { v7 = fmaf(c7, v7, vl); c7 *= cl; }
        }
#pragma unroll
        for (int h = 32; h >= 1; h >>= 1) {
            float vl = __shfl_up(v7, (unsigned)h);
            float vr = __shfl_down(v7, (unsigned)h);
            bool right = ((t & (2 * h - 1)) == (2 * h - 1));
            bool left  = ((t & (2 * h - 1)) == (h - 1));
            float nv = v7;
            if (right) nv = fmaf(c7, v7, vl);
            if (left)  nv = vr;
            v7 = nv;
        }
        v[7] = v7;
        c[7] = c7;
        float tmp;
        tmp = v[7]; v[7] = fmaf(c[7], v[7], v[3]); v[3] = tmp;
        tmp = v[3]; v[3] = fmaf(c[3], v[3], v[1]); v[1] = tmp;
        tmp = v[7]; v[7] = fmaf(c[7], v[7], v[5]); v[5] = tmp;
#pragma unroll
        for (int p = 0; p < 8; p += 2) {
            tmp = v[p+1]; v[p+1] = fmaf(c[p+1], v[p+1], v[p]); v[p] = tmp;
        }
#pragma unroll
        for (int i = 0; i < 8; ++i) {
            float Cv = x_dbl[(long)(base + l0 + i) * N_XDBL + D_INNER + D_STATE + n];
            yac[i] = fmaf(v[i], Cv, yac[i]);
        }
    }

    const float Dpd = Dp[d];
#pragma unroll
    for (int i = 0; i < 8; ++i) {
        float uv = fmaf(xr[i], Dpd, yac[i]) * zsiluT[(long)d * M_ROWS + base + l0 + i];
        uT[(long)d * M_ROWS + base + l0 + i] = uv;
    }
}

// ---------------------------------------------------------------------------
// Transpose + split: uT (1536,1024) fp32 -> u hi/lo (1024,1536) bf16.
// ---------------------------------------------------------------------------
__global__ __launch_bounds__(256) void transpose_split_kernel(
    const float* __restrict__ uT, ushort_t* __restrict__ uh, ushort_t* __restrict__ ul)
{
    __shared__ float T[64][65];
    const int m0 = blockIdx.x * 64;   // 0..960
    const int d0 = blockIdx.y * 64;   // 0..1472
    const int c  = threadIdx.x & 63;
    const int rr = threadIdx.x >> 6;
#pragma unroll
    for (int p = 0; p < 64; p += 4)
        T[p + rr][c] = uT[(long)(d0 + p + rr) * M_ROWS + m0 + c];
    __syncthreads();
#pragma unroll
    for (int p = 0; p < 64; p += 4) {
        int rm = p + rr;
        float v = T[c][rm];
        ushort_t h, l;
        split1(v, h, l);
        uh[(long)(m0 + rm) * D_INNER + d0 + c] = h;
        ul[(long)(m0 + rm) * D_INNER + d0 + c] = l;
    }
}

// ---------------------------------------------------------------------------
extern "C" void kernel_launch(void* const* d_in, const int* in_sizes, int n_in,
                              void* d_out, int out_size, void* d_ws, size_t ws_size,
                              hipStream_t stream)
{
    (void)in_sizes; (void)n_in; (void)out_size; (void)ws_size;

    const float* x      = (const float*)d_in[0];
    const float* W_in   = (const float*)d_in[1];
    const float* conv_w = (const float*)d_in[2];
    const float* conv_b = (const float*)d_in[3];
    const float* W_x    = (const float*)d_in[4];
    const float* W_dt   = (const float*)d_in[5];
    const float* b_dt   = (const float*)d_in[6];
    const float* A_log  = (const float*)d_in[7];
    const float* Dp     = (const float*)d_in[8];
    const float* W_out  = (const float*)d_in[9];
    float* out = (float*)d_out;

    // ---- workspace layout (floats). Aliasing:
    //   xz (12.6 MB) -> after conv: deltaT (lo half) + uT (hi half); after scan,
    //   u split overlays the deltaT half.  W_in split region reused for W_dt;
    //   W_x split region reused for W_out.
    float* ws = (float*)d_ws;
    long off = 0;
    float* xz     = ws + off; off += (long)M_ROWS * N_XZ;          // 3145728
    float* deltaT = xz;
    float* uT     = xz + (long)D_INNER * M_ROWS;
    ushort_t* u_h = (ushort_t*)xz;                                  // after scan
    ushort_t* u_l = (ushort_t*)xz + (long)M_ROWS * D_INNER;
    float* xconvT = ws + off; off += (long)D_INNER * M_ROWS;       // 1572864
    float* zsiluT = ws + off; off += (long)D_INNER * M_ROWS;       // 1572864
    float* x_dbl  = ws + off; off += (long)M_ROWS * N_XDBL;        // 1605632
    // weight splits (ushort): region1 = W_in / W_dt (2359296 el each)
    ushort_t* w1_h = (ushort_t*)(ws + off);
    ushort_t* w1_l = w1_h + (long)N_XZ * D_MODEL;  off += (long)N_XZ * D_MODEL; // 2359296 fl
    // region2 = W_x (2408448 el) / W_out (1179648 el)
    ushort_t* w2_h = (ushort_t*)(ws + off);
    ushort_t* w2_l = w2_h + (long)N_XDBL * D_INNER; off += (long)N_XDBL * D_INNER; // 2408448 fl
    // x split
    ushort_t* x_h = (ushort_t*)(ws + off);
    ushort_t* x_l = x_h + (long)M_ROWS * D_MODEL;  off += (long)M_ROWS * D_MODEL;
    // xconv split (1024,1536)
    ushort_t* xc_h = (ushort_t*)(ws + off);
    ushort_t* xc_l = xc_h + (long)M_ROWS * D_INNER; off += (long)M_ROWS * D_INNER;
    // x_dbl split (1024,1568)
    ushort_t* xd_h = (ushort_t*)(ws + off);
    ushort_t* xd_l = xd_h + (long)M_ROWS * N_XDBL;  off += (long)M_ROWS * N_XDBL;

    dim3 blk(256);

    // split x and W_in
    hipLaunchKernelGGL(split_kernel, dim3((M_ROWS * D_MODEL) / 1024), blk, 0, stream,
                       x, x_h, x_l, M_ROWS * D_MODEL);
    hipLaunchKernelGGL(split_kernel, dim3((N_XZ * D_MODEL) / 1024), blk, 0, stream,
                       W_in, w1_h, w1_l, N_XZ * D_MODEL);
    // 1) xz = x @ W_in^T   (M=1024, N=3072, K=768)
    hipLaunchKernelGGL((gemm_mfma<0>), dim3(N_XZ / 128, M_ROWS / 128), blk, 0, stream,
                       x_h, x_l, D_MODEL, w1_h, w1_l, D_MODEL,
                       xz, N_XZ, (ushort_t*)nullptr, (ushort_t*)nullptr,
                       (const float*)nullptr, N_XZ, D_MODEL);
    // split W_dt into region1 (W_in dead)
    hipLaunchKernelGGL(split_kernel, dim3((D_INNER * D_INNER) / 1024), blk, 0, stream,
                       W_dt, w1_h, w1_l, D_INNER * D_INNER);
    // 2) conv + silu
    hipLaunchKernelGGL(conv_silu_kernel, dim3((M_ROWS * D_INNER) / 256), blk, 0, stream,
                       xz, conv_w, conv_b, xconvT, zsiluT, xc_h, xc_l);
    // split W_x
    hipLaunchKernelGGL(split_kernel, dim3((N_XDBL * D_INNER) / 1024), blk, 0, stream,
                       W_x, w2_h, w2_l, N_XDBL * D_INNER);
    // 3) x_dbl = xconv @ W_x^T  (M=1024, N=1568, K=1536), +split output
    hipLaunchKernelGGL((gemm_mfma<2>), dim3((N_XDBL + 127) / 128, M_ROWS / 128), blk, 0, stream,
                       xc_h, xc_l, D_INNER, w2_h, w2_l, D_INNER,
                       x_dbl, N_XDBL, xd_h, xd_l,
                       (const float*)nullptr, N_XDBL, D_INNER);
    // split W_out into region2 (W_x dead)
    hipLaunchKernelGGL(split_kernel, dim3((D_MODEL * D_INNER) / 1024), blk, 0, stream,
                       W_out, w2_h, w2_l, D_MODEL * D_INNER);
    // 4) deltaT = softplus(W_dt @ x_dbl^T + b_dt)  (M=1536, N=1024, K=1536)
    hipLaunchKernelGGL((gemm_mfma<1>), dim3(M_ROWS / 128, D_INNER / 128), blk, 0, stream,
                       w1_h, w1_l, D_INNER, xd_h, xd_l, N_XDBL,
                       deltaT, M_ROWS, (ushort_t*)nullptr, (ushort_t*)nullptr,
                       b_dt, M_ROWS, D_INNER);
    // 5) scan -> uT
    hipLaunchKernelGGL(scan_kernel, dim3(BATCH * (D_INNER / 4)), blk, 0, stream,
                       deltaT, xconvT, zsiluT, x_dbl, A_log, Dp, uT);
    // 5b) transpose+split uT -> u hi/lo (overlays deltaT region; uT intact)
    hipLaunchKernelGGL(transpose_split_kernel, dim3(M_ROWS / 64, D_INNER / 64), blk, 0, stream,
                       uT, u_h, u_l);
    // 6) out = u @ W_out^T  (M=1024, N=768, K=1536)
    hipLaunchKernelGGL((gemm_mfma<0>), dim3(D_MODEL / 128, M_ROWS / 128), blk, 0, stream,
                       u_h, u_l, D_INNER, w2_h, w2_l, D_INNER,
                       out, D_MODEL, (ushort_t*)nullptr, (ushort_t*)nullptr,
                       (const float*)nullptr, D_MODEL, D_INNER);
}

// Round 4
// 410.720 us; speedup vs baseline: 2.6401x; 1.2913x over previous
//
#include <hip/hip_runtime.h>
#include <math.h>

#define D_MODEL 768
#define D_STATE 16
#define D_CONV  4
#define D_INNER 1536
#define BATCH   2
#define SEQ     512
#define M_ROWS  (BATCH * SEQ)            // 1024
#define N_XZ    (2 * D_INNER)            // 3072
#define N_XDBL  (D_INNER + 2 * D_STATE)  // 1568

typedef short  short8 __attribute__((ext_vector_type(8)));
typedef float  f32x4  __attribute__((ext_vector_type(4)));
typedef unsigned short ushort_t;

// ---- manual bf16 helpers (RNE), raw ushort storage ----
__device__ __forceinline__ ushort_t f2bf(float f) {
    unsigned int u = __float_as_uint(f);
    return (ushort_t)((u + 0x7fffu + ((u >> 16) & 1u)) >> 16);
}
__device__ __forceinline__ float bf2f(ushort_t s) {
    return __uint_as_float((unsigned int)s << 16);
}
__device__ __forceinline__ void split1(float x, ushort_t& h, ushort_t& l) {
    h = f2bf(x);
    l = f2bf(x - bf2f(h));
}

// async global(16B/lane) -> LDS (wave-uniform base + lane*16)
__device__ __forceinline__ void gld16(const ushort_t* g, void* l) {
    __builtin_amdgcn_global_load_lds((const __attribute__((address_space(1))) void*)g,
                                     (__attribute__((address_space(3))) void*)l, 16, 0, 0);
}

// ---------------------------------------------------------------------------
// Split fp32 -> (hi, lo) bf16.  n multiple of 1024; 4 elements/thread.
// ---------------------------------------------------------------------------
__global__ __launch_bounds__(256) void split_kernel(
    const float* __restrict__ in, ushort_t* __restrict__ hi,
    ushort_t* __restrict__ lo, int n)
{
    int i = (blockIdx.x * 256 + threadIdx.x) * 4;
    if (i >= n) return;
    float4 v = *(const float4*)(in + i);
    ushort_t h0,h1,h2,h3,l0,l1,l2,l3;
    split1(v.x,h0,l0); split1(v.y,h1,l1); split1(v.z,h2,l2); split1(v.w,h3,l3);
    hi[i+0]=h0; hi[i+1]=h1; hi[i+2]=h2; hi[i+3]=h3;
    lo[i+0]=l0; lo[i+1]=l1; lo[i+2]=l2; lo[i+3]=l3;
}

// ---------------------------------------------------------------------------
// Split-bf16 MFMA GEMM, double-buffered async staging.
//   C[m,n] = epi( sum_k A[m,k]*B[n,k] );  A (M,K), B (N,K) hi/lo bf16.
// 128x128 block tile, 4 waves of 64x64, mfma_f32_16x16x32_bf16, 3 products.
// LDS fragment-order layout; global_load_lds dwordx4 staging into alternating
// 32 KB buffers; one barrier per K-iter, loads covered by MFMA block.
// EPI: 0 plain fp32; 1 +bias[row]+softplus; 2 fp32 + split-bf16 + BCT
// (cols >= D_INNER stored transposed fp32 to BCT[(col-D_INNER)*M_ROWS+row]).
// Requires M%128==0, K%32==0; N tail guarded (wave-uniform per 16-row group).
// ---------------------------------------------------------------------------
template <int EPI>
__global__ __launch_bounds__(256) void gemm_mfma(
    const ushort_t* __restrict__ Ah, const ushort_t* __restrict__ Al, int lda,
    const ushort_t* __restrict__ Bh, const ushort_t* __restrict__ Bl, int ldb,
    float* __restrict__ C, int ldc,
    ushort_t* __restrict__ Ch, ushort_t* __restrict__ Cl,
    float* __restrict__ BCT,
    const float* __restrict__ bias,
    int N, int K)
{
    __shared__ short8 lds[2][4][512];     // [buf][AH,AL,BH,BL][slot] = 64 KB

    const int tid  = threadIdx.x;
    const int w    = tid >> 6;
    const int lane = tid & 63;
    const int bm = blockIdx.y * 128;
    const int bn = blockIdx.x * 128;
    const int lq = lane >> 4;        // k-quad
    const int lr = lane & 15;        // row within 16

    f32x4 acc[4][4] = {};

    // stage tile at k0 into lds[buf]
    auto stage = [&](int k0, int buf) {
#pragma unroll
        for (int r = 0; r < 2; ++r) {
            const int MT = r * 4 + w;                // 0..7 (16-row group)
            const int slot = MT * 64 + lane;
            const long ka = (long)k0 + lq * 8;
            const int mA = bm + MT * 16 + lr;
            gld16(Ah + (long)mA * lda + ka, &lds[buf][0][slot]);
            gld16(Al + (long)mA * lda + ka, &lds[buf][1][slot]);
            if (bn + MT * 16 < N) {                  // wave-uniform guard
                const int mB = bn + MT * 16 + lr;
                gld16(Bh + (long)mB * ldb + ka, &lds[buf][2][slot]);
                gld16(Bl + (long)mB * ldb + ka, &lds[buf][3][slot]);
            }
        }
    };

    stage(0, 0);
    __syncthreads();

    const int nK = K >> 5;
    for (int ki = 0; ki < nK; ++ki) {
        const int buf = ki & 1;
        if (ki + 1 < nK) stage((ki + 1) << 5, buf ^ 1);

        short8 afh[4], afl[4], bfh[4], bfl[4];
#pragma unroll
        for (int mt = 0; mt < 4; ++mt) {
            int MT = (w & 1) * 4 + mt;
            afh[mt] = lds[buf][0][MT * 64 + lane];
            afl[mt] = lds[buf][1][MT * 64 + lane];
        }
#pragma unroll
        for (int nt = 0; nt < 4; ++nt) {
            int NT = (w >> 1) * 4 + nt;
            bfh[nt] = lds[buf][2][NT * 64 + lane];
            bfl[nt] = lds[buf][3][NT * 64 + lane];
        }
#pragma unroll
        for (int mt = 0; mt < 4; ++mt)
#pragma unroll
            for (int nt = 0; nt < 4; ++nt) {
                acc[mt][nt] = __builtin_amdgcn_mfma_f32_16x16x32_bf16(afl[mt], bfh[nt], acc[mt][nt], 0, 0, 0);
                acc[mt][nt] = __builtin_amdgcn_mfma_f32_16x16x32_bf16(afh[mt], bfl[nt], acc[mt][nt], 0, 0, 0);
                acc[mt][nt] = __builtin_amdgcn_mfma_f32_16x16x32_bf16(afh[mt], bfh[nt], acc[mt][nt], 0, 0, 0);
            }
        __syncthreads();   // drains staging loads for buf^1; frees buf for next stage
    }

    // epilogue: C/D layout col = lane&15, row = (lane>>4)*4 + reg  [m89/m91]
    const int wm = (w & 1) * 64;
    const int wn = (w >> 1) * 64;
    const int col0 = lane & 15;
    const int quad = lane >> 4;
#pragma unroll
    for (int mt = 0; mt < 4; ++mt)
#pragma unroll
        for (int nt = 0; nt < 4; ++nt)
#pragma unroll
            for (int r = 0; r < 4; ++r) {
                int row = bm + wm + mt * 16 + quad * 4 + r;
                int col = bn + wn + nt * 16 + col0;
                if (col >= N) continue;
                float v = acc[mt][nt][r];
                if (EPI == 1) {
                    v += bias[row];
                    v = fmaxf(v, 0.f) + log1pf(expf(-fabsf(v)));  // softplus
                }
                C[(long)row * ldc + col] = v;
                if (EPI == 2) {
                    ushort_t h, l;
                    split1(v, h, l);
                    Ch[(long)row * ldc + col] = h;
                    Cl[(long)row * ldc + col] = l;
                    if (col >= D_INNER)
                        BCT[(long)(col - D_INNER) * M_ROWS + row] = v;
                }
            }
}

// ---------------------------------------------------------------------------
// Depthwise causal conv (width 4) + bias + SiLU.
// ---------------------------------------------------------------------------
__global__ __launch_bounds__(256) void conv_silu_kernel(
    const float* __restrict__ xz,
    const float* __restrict__ conv_w,
    const float* __restrict__ conv_b,
    float* __restrict__ xconvT,
    float* __restrict__ zsiluT,
    ushort_t* __restrict__ xch,
    ushort_t* __restrict__ xcl)
{
    int idx = blockIdx.x * blockDim.x + threadIdx.x;
    if (idx >= M_ROWS * D_INNER) return;
    int d = idx % D_INNER;
    int r = idx / D_INNER;
    int l = r % SEQ;
    float acc = conv_b[d];
#pragma unroll
    for (int k = 0; k < D_CONV; ++k) {
        if (l - (D_CONV - 1) + k >= 0)
            acc = fmaf(conv_w[d * D_CONV + k],
                       xz[(long)(r - (D_CONV - 1 - k)) * N_XZ + d], acc);
    }
    float s = acc / (1.f + expf(-acc));
    xconvT[(long)d * M_ROWS + r] = s;
    ushort_t h, lo;
    split1(s, h, lo);
    xch[idx] = h;
    xcl[idx] = lo;
    float z = xz[(long)r * N_XZ + D_INNER + d];
    zsiluT[(long)d * M_ROWS + r] = z / (1.f + expf(-z));
}

// ---------------------------------------------------------------------------
// Wave-per-(b,d) register scan. No LDS, no barriers. B/C read coalesced from
// BCT (rows 0..15 = B states, 16..31 = C states; each row is (b*512+l)).
// ---------------------------------------------------------------------------
__global__ __launch_bounds__(256) void scan_kernel(
    const float* __restrict__ deltaT,
    const float* __restrict__ xconvT,
    const float* __restrict__ zsiluT,
    const float* __restrict__ BCT,     // (32, 1024)
    const float* __restrict__ A_log,
    const float* __restrict__ Dp,
    float* __restrict__ uT)
{
    const int bid = blockIdx.x;
    const int b   = bid / (D_INNER / 4);
    const int dg  = bid % (D_INNER / 4);
    const int tid = threadIdx.x;
    const int w   = tid >> 6;
    const int t   = tid & 63;
    const int d   = dg * 4 + w;
    const int base = b * SEQ;
    const int l0 = 8 * t;

    float dl[8], xr[8], yac[8];
#pragma unroll
    for (int i = 0; i < 8; ++i) {
        dl[i] = deltaT[(long)d * M_ROWS + base + l0 + i];
        xr[i] = xconvT[(long)d * M_ROWS + base + l0 + i];
        yac[i] = 0.f;
    }

    for (int n = 0; n < D_STATE; ++n) {
        const float Adn = -expf(A_log[d * D_STATE + n]);
        const float4* Bp = (const float4*)(BCT + (long)n * M_ROWS + base + l0);
        float4 b0 = Bp[0], b1 = Bp[1];
        float Bv[8] = {b0.x, b0.y, b0.z, b0.w, b1.x, b1.y, b1.z, b1.w};
        float c[8], v[8];
#pragma unroll
        for (int i = 0; i < 8; ++i) {
            c[i] = expf(dl[i] * Adn) + 1e-12f;
            v[i] = fabsf(dl[i] * Bv[i] * xr[i]) + 1e-12f;
        }
        // up-sweep in-lane (levels 0..2)
#pragma unroll
        for (int p = 0; p < 8; p += 2) { v[p+1] = fmaf(c[p+1], v[p+1], v[p]); c[p+1] *= c[p]; }
        v[3] = fmaf(c[3], v[3], v[1]); c[3] *= c[1];
        v[7] = fmaf(c[7], v[7], v[5]); c[7] *= c[5];
        v[7] = fmaf(c[7], v[7], v[3]); c[7] *= c[3];
        // up-sweep cross-lane (levels 3..8)
        float c7 = c[7], v7 = v[7];
#pragma unroll
        for (int h = 1; h <= 32; h <<= 1) {
            float vl = __shfl_up(v7, (unsigned)h);
            float cl = __shfl_up(c7, (unsigned)h);
            bool right = ((t & (2 * h - 1)) == (2 * h - 1));
            if (right) { v7 = fmaf(c7, v7, vl); c7 *= cl; }
        }
        // down-sweep cross-lane (levels 8..3)
#pragma unroll
        for (int h = 32; h >= 1; h >>= 1) {
            float vl = __shfl_up(v7, (unsigned)h);
            float vr = __shfl_down(v7, (unsigned)h);
            bool right = ((t & (2 * h - 1)) == (2 * h - 1));
            bool left  = ((t & (2 * h - 1)) == (h - 1));
            float nv = v7;
            if (right) nv = fmaf(c7, v7, vl);
            if (left)  nv = vr;
            v7 = nv;
        }
        v[7] = v7;
        c[7] = c7;
        // down-sweep in-lane (levels 2..0)
        float tmp;
        tmp = v[7]; v[7] = fmaf(c[7], v[7], v[3]); v[3] = tmp;
        tmp = v[3]; v[3] = fmaf(c[3], v[3], v[1]); v[1] = tmp;
        tmp = v[7]; v[7] = fmaf(c[7], v[7], v[5]); v[5] = tmp;
#pragma unroll
        for (int p = 0; p < 8; p += 2) {
            tmp = v[p+1]; v[p+1] = fmaf(c[p+1], v[p+1], v[p]); v[p] = tmp;
        }
        // contract with Cmat (coalesced)
        const float4* Cp = (const float4*)(BCT + (long)(16 + n) * M_ROWS + base + l0);
        float4 c0 = Cp[0], c1 = Cp[1];
        float Cv[8] = {c0.x, c0.y, c0.z, c0.w, c1.x, c1.y, c1.z, c1.w};
#pragma unroll
        for (int i = 0; i < 8; ++i) yac[i] = fmaf(v[i], Cv[i], yac[i]);
    }

    const float Dpd = Dp[d];
#pragma unroll
    for (int i = 0; i < 8; ++i) {
        float uv = fmaf(xr[i], Dpd, yac[i]) * zsiluT[(long)d * M_ROWS + base + l0 + i];
        uT[(long)d * M_ROWS + base + l0 + i] = uv;
    }
}

// ---------------------------------------------------------------------------
// Transpose + split: uT (1536,1024) fp32 -> u hi/lo (1024,1536) bf16.
// ---------------------------------------------------------------------------
__global__ __launch_bounds__(256) void transpose_split_kernel(
    const float* __restrict__ uT, ushort_t* __restrict__ uh, ushort_t* __restrict__ ul)
{
    __shared__ float T[64][65];
    const int m0 = blockIdx.x * 64;
    const int d0 = blockIdx.y * 64;
    const int c  = threadIdx.x & 63;
    const int rr = threadIdx.x >> 6;
#pragma unroll
    for (int p = 0; p < 64; p += 4)
        T[p + rr][c] = uT[(long)(d0 + p + rr) * M_ROWS + m0 + c];
    __syncthreads();
#pragma unroll
    for (int p = 0; p < 64; p += 4) {
        int rm = p + rr;
        float v = T[c][rm];
        ushort_t h, l;
        split1(v, h, l);
        uh[(long)(m0 + rm) * D_INNER + d0 + c] = h;
        ul[(long)(m0 + rm) * D_INNER + d0 + c] = l;
    }
}

// ---------------------------------------------------------------------------
extern "C" void kernel_launch(void* const* d_in, const int* in_sizes, int n_in,
                              void* d_out, int out_size, void* d_ws, size_t ws_size,
                              hipStream_t stream)
{
    (void)in_sizes; (void)n_in; (void)out_size; (void)ws_size;

    const float* x      = (const float*)d_in[0];
    const float* W_in   = (const float*)d_in[1];
    const float* conv_w = (const float*)d_in[2];
    const float* conv_b = (const float*)d_in[3];
    const float* W_x    = (const float*)d_in[4];
    const float* W_dt   = (const float*)d_in[5];
    const float* b_dt   = (const float*)d_in[6];
    const float* A_log  = (const float*)d_in[7];
    const float* Dp     = (const float*)d_in[8];
    const float* W_out  = (const float*)d_in[9];
    float* out = (float*)d_out;

    float* ws = (float*)d_ws;
    long off = 0;
    float* xz     = ws + off; off += (long)M_ROWS * N_XZ;
    float* deltaT = xz;
    float* uT     = xz + (long)D_INNER * M_ROWS;
    ushort_t* u_h = (ushort_t*)xz;
    ushort_t* u_l = (ushort_t*)xz + (long)M_ROWS * D_INNER;
    float* xconvT = ws + off; off += (long)D_INNER * M_ROWS;
    float* zsiluT = ws + off; off += (long)D_INNER * M_ROWS;
    float* x_dbl  = ws + off; off += (long)M_ROWS * N_XDBL;
    ushort_t* w1_h = (ushort_t*)(ws + off);
    ushort_t* w1_l = w1_h + (long)N_XZ * D_MODEL;   off += (long)N_XZ * D_MODEL;
    ushort_t* w2_h = (ushort_t*)(ws + off);
    ushort_t* w2_l = w2_h + (long)N_XDBL * D_INNER; off += (long)N_XDBL * D_INNER;
    ushort_t* x_h = (ushort_t*)(ws + off);
    ushort_t* x_l = x_h + (long)M_ROWS * D_MODEL;   off += (long)M_ROWS * D_MODEL;
    ushort_t* xc_h = (ushort_t*)(ws + off);
    ushort_t* xc_l = xc_h + (long)M_ROWS * D_INNER; off += (long)M_ROWS * D_INNER;
    ushort_t* xd_h = (ushort_t*)(ws + off);
    ushort_t* xd_l = xd_h + (long)M_ROWS * N_XDBL;  off += (long)M_ROWS * N_XDBL;
    float* BCT = ws + off; off += (long)2 * D_STATE * M_ROWS;   // 32x1024 fp32

    dim3 blk(256);

    hipLaunchKernelGGL(split_kernel, dim3((M_ROWS * D_MODEL) / 1024), blk, 0, stream,
                       x, x_h, x_l, M_ROWS * D_MODEL);
    hipLaunchKernelGGL(split_kernel, dim3((N_XZ * D_MODEL) / 1024), blk, 0, stream,
                       W_in, w1_h, w1_l, N_XZ * D_MODEL);
    // 1) xz = x @ W_in^T
    hipLaunchKernelGGL((gemm_mfma<0>), dim3(N_XZ / 128, M_ROWS / 128), blk, 0, stream,
                       x_h, x_l, D_MODEL, w1_h, w1_l, D_MODEL,
                       xz, N_XZ, (ushort_t*)nullptr, (ushort_t*)nullptr,
                       (float*)nullptr, (const float*)nullptr, N_XZ, D_MODEL);
    hipLaunchKernelGGL(split_kernel, dim3((D_INNER * D_INNER) / 1024), blk, 0, stream,
                       W_dt, w1_h, w1_l, D_INNER * D_INNER);
    // 2) conv + silu
    hipLaunchKernelGGL(conv_silu_kernel, dim3((M_ROWS * D_INNER) / 256), blk, 0, stream,
                       xz, conv_w, conv_b, xconvT, zsiluT, xc_h, xc_l);
    hipLaunchKernelGGL(split_kernel, dim3((N_XDBL * D_INNER) / 1024), blk, 0, stream,
                       W_x, w2_h, w2_l, N_XDBL * D_INNER);
    // 3) x_dbl = xconv @ W_x^T  (+split, +BCT transposed B/C cols)
    hipLaunchKernelGGL((gemm_mfma<2>), dim3((N_XDBL + 127) / 128, M_ROWS / 128), blk, 0, stream,
                       xc_h, xc_l, D_INNER, w2_h, w2_l, D_INNER,
                       x_dbl, N_XDBL, xd_h, xd_l,
                       BCT, (const float*)nullptr, N_XDBL, D_INNER);
    hipLaunchKernelGGL(split_kernel, dim3((D_MODEL * D_INNER) / 1024), blk, 0, stream,
                       W_out, w2_h, w2_l, D_MODEL * D_INNER);
    // 4) deltaT = softplus(W_dt @ x_dbl^T + b_dt)
    hipLaunchKernelGGL((gemm_mfma<1>), dim3(M_ROWS / 128, D_INNER / 128), blk, 0, stream,
                       w1_h, w1_l, D_INNER, xd_h, xd_l, N_XDBL,
                       deltaT, M_ROWS, (ushort_t*)nullptr, (ushort_t*)nullptr,
                       (float*)nullptr, b_dt, M_ROWS, D_INNER);
    // 5) scan -> uT
    hipLaunchKernelGGL(scan_kernel, dim3(BATCH * (D_INNER / 4)), blk, 0, stream,
                       deltaT, xconvT, zsiluT, BCT, A_log, Dp, uT);
    // 5b) transpose+split uT -> u hi/lo
    hipLaunchKernelGGL(transpose_split_kernel, dim3(M_ROWS / 64, D_INNER / 64), blk, 0, stream,
                       uT, u_h, u_l);
    // 6) out = u @ W_out^T
    hipLaunchKernelGGL((gemm_mfma<0>), dim3(D_MODEL / 128, M_ROWS / 128), blk, 0, stream,
                       u_h, u_l, D_INNER, w2_h, w2_l, D_INNER,
                       out, D_MODEL, (ushort_t*)nullptr, (ushort_t*)nullptr,
                       (float*)nullptr, (const float*)nullptr, D_MODEL, D_INNER);
}

// Round 5
// 347.117 us; speedup vs baseline: 3.1239x; 1.1832x over previous
//
#include <hip/hip_runtime.h>
#include <math.h>

#define D_MODEL 768
#define D_STATE 16
#define D_CONV  4
#define D_INNER 1536
#define BATCH   2
#define SEQ     512
#define M_ROWS  (BATCH * SEQ)            // 1024
#define N_XZ    (2 * D_INNER)            // 3072
#define N_XDBL  (D_INNER + 2 * D_STATE)  // 1568

typedef short  short8 __attribute__((ext_vector_type(8)));
typedef float  f32x4  __attribute__((ext_vector_type(4)));
typedef unsigned short ushort_t;

// ---- manual bf16 helpers (RNE), raw ushort storage ----
__device__ __forceinline__ ushort_t f2bf(float f) {
    unsigned int u = __float_as_uint(f);
    return (ushort_t)((u + 0x7fffu + ((u >> 16) & 1u)) >> 16);
}
__device__ __forceinline__ float bf2f(ushort_t s) {
    return __uint_as_float((unsigned int)s << 16);
}
__device__ __forceinline__ void split1(float x, ushort_t& h, ushort_t& l) {
    h = f2bf(x);
    l = f2bf(x - bf2f(h));
}

// ---------------------------------------------------------------------------
// Split fp32 -> (hi, lo) bf16.  n multiple of 1024; 4 elements/thread.
// ---------------------------------------------------------------------------
__global__ __launch_bounds__(256) void split_kernel(
    const float* __restrict__ in, ushort_t* __restrict__ hi,
    ushort_t* __restrict__ lo, int n)
{
    int i = (blockIdx.x * 256 + threadIdx.x) * 4;
    if (i >= n) return;
    float4 v = *(const float4*)(in + i);
    ushort_t h0,h1,h2,h3,l0,l1,l2,l3;
    split1(v.x,h0,l0); split1(v.y,h1,l1); split1(v.z,h2,l2); split1(v.w,h3,l3);
    hi[i+0]=h0; hi[i+1]=h1; hi[i+2]=h2; hi[i+3]=h3;
    lo[i+0]=l0; lo[i+1]=l1; lo[i+2]=l2; lo[i+3]=l3;
}

// ---------------------------------------------------------------------------
// Split-bf16 MFMA GEMM — one wave per block, 64x64 tile, NO LDS, NO barriers.
//   C[m,n] = epi( sum_k A[m,k]*B[n,k] );  A (M,K), B (N,K) as hi/lo bf16.
// The mfma_f32_16x16x32_bf16 A/B fragment for lane L is the contiguous 16 B
// at row (tile + (L&15)), k-offset (L>>4)*8 — loaded straight from global
// (L2/L3-resident), software-pipelined with two register fragment sets.
// 3-product split: Al*Bh + Ah*Bl + Ah*Bh, fp32 accum (bit-identical to R4).
// EPI: 0 plain fp32; 1 +bias[row]+softplus; 2 fp32 + split-bf16 + BCT
// (cols >= D_INNER also stored transposed fp32 to BCT[(col-D_INNER)*M_ROWS+row]).
// Requires M%64==0, K%64==0; N tail: B row clamped (read-valid), store guarded.
// ---------------------------------------------------------------------------
template <int EPI>
__global__ __launch_bounds__(64) void gemm_mfma(
    const ushort_t* __restrict__ Ah, const ushort_t* __restrict__ Al, int lda,
    const ushort_t* __restrict__ Bh, const ushort_t* __restrict__ Bl, int ldb,
    float* __restrict__ C, int ldc,
    ushort_t* __restrict__ Ch, ushort_t* __restrict__ Cl,
    float* __restrict__ BCT,
    const float* __restrict__ bias,
    int N, int K)
{
    const int lane = threadIdx.x;
    const int bm = blockIdx.y * 64;
    const int bn = blockIdx.x * 64;
    const int lr = lane & 15;
    const int lq = lane >> 4;

    long oA[4], oB[4];
#pragma unroll
    for (int i = 0; i < 4; ++i) {
        oA[i] = (long)(bm + i * 16 + lr) * lda + lq * 8;
        int rB = bn + i * 16 + lr;
        if (rB >= N) rB = N - 1;               // clamp: stays in-buffer, discarded
        oB[i] = (long)rB * ldb + lq * 8;
    }

    f32x4 acc[4][4] = {};
    short8 a0h[4], a0l[4], b0h[4], b0l[4];
    short8 a1h[4], a1l[4], b1h[4], b1l[4];

    auto loadset = [&](short8* ah, short8* al, short8* bh, short8* bl, int k0) {
#pragma unroll
        for (int i = 0; i < 4; ++i) {
            ah[i] = *(const short8*)(Ah + oA[i] + k0);
            al[i] = *(const short8*)(Al + oA[i] + k0);
            bh[i] = *(const short8*)(Bh + oB[i] + k0);
            bl[i] = *(const short8*)(Bl + oB[i] + k0);
        }
    };
    auto mfmaset = [&](short8* ah, short8* al, short8* bh, short8* bl) {
#pragma unroll
        for (int mt = 0; mt < 4; ++mt)
#pragma unroll
            for (int nt = 0; nt < 4; ++nt) {
                acc[mt][nt] = __builtin_amdgcn_mfma_f32_16x16x32_bf16(al[mt], bh[nt], acc[mt][nt], 0, 0, 0);
                acc[mt][nt] = __builtin_amdgcn_mfma_f32_16x16x32_bf16(ah[mt], bl[nt], acc[mt][nt], 0, 0, 0);
                acc[mt][nt] = __builtin_amdgcn_mfma_f32_16x16x32_bf16(ah[mt], bh[nt], acc[mt][nt], 0, 0, 0);
            }
    };

    const int nPair = K >> 6;                  // K % 64 == 0 for all users
    loadset(a0h, a0l, b0h, b0l, 0);
    int k = 0;
    for (int it = 0; it < nPair; ++it) {
        loadset(a1h, a1l, b1h, b1l, k + 32);   // in flight during MFMA set 0
        mfmaset(a0h, a0l, b0h, b0l);
        if (it + 1 < nPair)
            loadset(a0h, a0l, b0h, b0l, k + 64); // in flight during MFMA set 1
        mfmaset(a1h, a1l, b1h, b1l);
        k += 64;
    }

    // epilogue: C/D layout col = lane&15, row = (lane>>4)*4 + reg  [m89/m91]
    const int col0 = lane & 15;
    const int quad = lane >> 4;
#pragma unroll
    for (int mt = 0; mt < 4; ++mt)
#pragma unroll
        for (int nt = 0; nt < 4; ++nt)
#pragma unroll
            for (int r = 0; r < 4; ++r) {
                int row = bm + mt * 16 + quad * 4 + r;
                int col = bn + nt * 16 + col0;
                if (col >= N) continue;
                float v = acc[mt][nt][r];
                if (EPI == 1) {
                    v += bias[row];
                    v = fmaxf(v, 0.f) + log1pf(expf(-fabsf(v)));  // softplus
                }
                C[(long)row * ldc + col] = v;
                if (EPI == 2) {
                    ushort_t h, l;
                    split1(v, h, l);
                    Ch[(long)row * ldc + col] = h;
                    Cl[(long)row * ldc + col] = l;
                    if (col >= D_INNER)
                        BCT[(long)(col - D_INNER) * M_ROWS + row] = v;
                }
            }
}

// ---------------------------------------------------------------------------
// Depthwise causal conv (width 4) + bias + SiLU.
// ---------------------------------------------------------------------------
__global__ __launch_bounds__(256) void conv_silu_kernel(
    const float* __restrict__ xz,
    const float* __restrict__ conv_w,
    const float* __restrict__ conv_b,
    float* __restrict__ xconvT,
    float* __restrict__ zsiluT,
    ushort_t* __restrict__ xch,
    ushort_t* __restrict__ xcl)
{
    int idx = blockIdx.x * blockDim.x + threadIdx.x;
    if (idx >= M_ROWS * D_INNER) return;
    int d = idx % D_INNER;
    int r = idx / D_INNER;
    int l = r % SEQ;
    float acc = conv_b[d];
#pragma unroll
    for (int k = 0; k < D_CONV; ++k) {
        if (l - (D_CONV - 1) + k >= 0)
            acc = fmaf(conv_w[d * D_CONV + k],
                       xz[(long)(r - (D_CONV - 1 - k)) * N_XZ + d], acc);
    }
    float s = acc / (1.f + expf(-acc));
    xconvT[(long)d * M_ROWS + r] = s;
    ushort_t h, lo;
    split1(s, h, lo);
    xch[idx] = h;
    xcl[idx] = lo;
    float z = xz[(long)r * N_XZ + D_INNER + d];
    zsiluT[(long)d * M_ROWS + r] = z / (1.f + expf(-z));
}

// ---------------------------------------------------------------------------
// Wave-per-(b,d) register scan. No LDS, no barriers. B/C read coalesced from
// BCT (rows 0..15 = B states, 16..31 = C states; each row is (b*512+l)).
// ---------------------------------------------------------------------------
__global__ __launch_bounds__(256) void scan_kernel(
    const float* __restrict__ deltaT,
    const float* __restrict__ xconvT,
    const float* __restrict__ zsiluT,
    const float* __restrict__ BCT,     // (32, 1024)
    const float* __restrict__ A_log,
    const float* __restrict__ Dp,
    float* __restrict__ uT)
{
    const int bid = blockIdx.x;
    const int b   = bid / (D_INNER / 4);
    const int dg  = bid % (D_INNER / 4);
    const int tid = threadIdx.x;
    const int w   = tid >> 6;
    const int t   = tid & 63;
    const int d   = dg * 4 + w;
    const int base = b * SEQ;
    const int l0 = 8 * t;

    float dl[8], xr[8], yac[8];
#pragma unroll
    for (int i = 0; i < 8; ++i) {
        dl[i] = deltaT[(long)d * M_ROWS + base + l0 + i];
        xr[i] = xconvT[(long)d * M_ROWS + base + l0 + i];
        yac[i] = 0.f;
    }

    for (int n = 0; n < D_STATE; ++n) {
        const float Adn = -expf(A_log[d * D_STATE + n]);
        const float4* Bp = (const float4*)(BCT + (long)n * M_ROWS + base + l0);
        float4 b0 = Bp[0], b1 = Bp[1];
        float Bv[8] = {b0.x, b0.y, b0.z, b0.w, b1.x, b1.y, b1.z, b1.w};
        float c[8], v[8];
#pragma unroll
        for (int i = 0; i < 8; ++i) {
            c[i] = expf(dl[i] * Adn) + 1e-12f;
            v[i] = fabsf(dl[i] * Bv[i] * xr[i]) + 1e-12f;
        }
        // up-sweep in-lane (levels 0..2)
#pragma unroll
        for (int p = 0; p < 8; p += 2) { v[p+1] = fmaf(c[p+1], v[p+1], v[p]); c[p+1] *= c[p]; }
        v[3] = fmaf(c[3], v[3], v[1]); c[3] *= c[1];
        v[7] = fmaf(c[7], v[7], v[5]); c[7] *= c[5];
        v[7] = fmaf(c[7], v[7], v[3]); c[7] *= c[3];
        // up-sweep cross-lane (levels 3..8)
        float c7 = c[7], v7 = v[7];
#pragma unroll
        for (int h = 1; h <= 32; h <<= 1) {
            float vl = __shfl_up(v7, (unsigned)h);
            float cl = __shfl_up(c7, (unsigned)h);
            bool right = ((t & (2 * h - 1)) == (2 * h - 1));
            if (right) { v7 = fmaf(c7, v7, vl); c7 *= cl; }
        }
        // down-sweep cross-lane (levels 8..3)
#pragma unroll
        for (int h = 32; h >= 1; h >>= 1) {
            float vl = __shfl_up(v7, (unsigned)h);
            float vr = __shfl_down(v7, (unsigned)h);
            bool right = ((t & (2 * h - 1)) == (2 * h - 1));
            bool left  = ((t & (2 * h - 1)) == (h - 1));
            float nv = v7;
            if (right) nv = fmaf(c7, v7, vl);
            if (left)  nv = vr;
            v7 = nv;
        }
        v[7] = v7;
        c[7] = c7;
        // down-sweep in-lane (levels 2..0)
        float tmp;
        tmp = v[7]; v[7] = fmaf(c[7], v[7], v[3]); v[3] = tmp;
        tmp = v[3]; v[3] = fmaf(c[3], v[3], v[1]); v[1] = tmp;
        tmp = v[7]; v[7] = fmaf(c[7], v[7], v[5]); v[5] = tmp;
#pragma unroll
        for (int p = 0; p < 8; p += 2) {
            tmp = v[p+1]; v[p+1] = fmaf(c[p+1], v[p+1], v[p]); v[p] = tmp;
        }
        // contract with Cmat (coalesced)
        const float4* Cp = (const float4*)(BCT + (long)(16 + n) * M_ROWS + base + l0);
        float4 c0 = Cp[0], c1 = Cp[1];
        float Cv[8] = {c0.x, c0.y, c0.z, c0.w, c1.x, c1.y, c1.z, c1.w};
#pragma unroll
        for (int i = 0; i < 8; ++i) yac[i] = fmaf(v[i], Cv[i], yac[i]);
    }

    const float Dpd = Dp[d];
#pragma unroll
    for (int i = 0; i < 8; ++i) {
        float uv = fmaf(xr[i], Dpd, yac[i]) * zsiluT[(long)d * M_ROWS + base + l0 + i];
        uT[(long)d * M_ROWS + base + l0 + i] = uv;
    }
}

// ---------------------------------------------------------------------------
// Transpose + split: uT (1536,1024) fp32 -> u hi/lo (1024,1536) bf16.
// ---------------------------------------------------------------------------
__global__ __launch_bounds__(256) void transpose_split_kernel(
    const float* __restrict__ uT, ushort_t* __restrict__ uh, ushort_t* __restrict__ ul)
{
    __shared__ float T[64][65];
    const int m0 = blockIdx.x * 64;
    const int d0 = blockIdx.y * 64;
    const int c  = threadIdx.x & 63;
    const int rr = threadIdx.x >> 6;
#pragma unroll
    for (int p = 0; p < 64; p += 4)
        T[p + rr][c] = uT[(long)(d0 + p + rr) * M_ROWS + m0 + c];
    __syncthreads();
#pragma unroll
    for (int p = 0; p < 64; p += 4) {
        int rm = p + rr;
        float v = T[c][rm];
        ushort_t h, l;
        split1(v, h, l);
        uh[(long)(m0 + rm) * D_INNER + d0 + c] = h;
        ul[(long)(m0 + rm) * D_INNER + d0 + c] = l;
    }
}

// ---------------------------------------------------------------------------
extern "C" void kernel_launch(void* const* d_in, const int* in_sizes, int n_in,
                              void* d_out, int out_size, void* d_ws, size_t ws_size,
                              hipStream_t stream)
{
    (void)in_sizes; (void)n_in; (void)out_size; (void)ws_size;

    const float* x      = (const float*)d_in[0];
    const float* W_in   = (const float*)d_in[1];
    const float* conv_w = (const float*)d_in[2];
    const float* conv_b = (const float*)d_in[3];
    const float* W_x    = (const float*)d_in[4];
    const float* W_dt   = (const float*)d_in[5];
    const float* b_dt   = (const float*)d_in[6];
    const float* A_log  = (const float*)d_in[7];
    const float* Dp     = (const float*)d_in[8];
    const float* W_out  = (const float*)d_in[9];
    float* out = (float*)d_out;

    float* ws = (float*)d_ws;
    long off = 0;
    float* xz     = ws + off; off += (long)M_ROWS * N_XZ;
    float* deltaT = xz;
    float* uT     = xz + (long)D_INNER * M_ROWS;
    ushort_t* u_h = (ushort_t*)xz;
    ushort_t* u_l = (ushort_t*)xz + (long)M_ROWS * D_INNER;
    float* xconvT = ws + off; off += (long)D_INNER * M_ROWS;
    float* zsiluT = ws + off; off += (long)D_INNER * M_ROWS;
    float* x_dbl  = ws + off; off += (long)M_ROWS * N_XDBL;
    ushort_t* w1_h = (ushort_t*)(ws + off);
    ushort_t* w1_l = w1_h + (long)N_XZ * D_MODEL;   off += (long)N_XZ * D_MODEL;
    ushort_t* w2_h = (ushort_t*)(ws + off);
    ushort_t* w2_l = w2_h + (long)N_XDBL * D_INNER; off += (long)N_XDBL * D_INNER;
    ushort_t* x_h = (ushort_t*)(ws + off);
    ushort_t* x_l = x_h + (long)M_ROWS * D_MODEL;   off += (long)M_ROWS * D_MODEL;
    ushort_t* xc_h = (ushort_t*)(ws + off);
    ushort_t* xc_l = xc_h + (long)M_ROWS * D_INNER; off += (long)M_ROWS * D_INNER;
    ushort_t* xd_h = (ushort_t*)(ws + off);
    ushort_t* xd_l = xd_h + (long)M_ROWS * N_XDBL;  off += (long)M_ROWS * N_XDBL;
    float* BCT = ws + off; off += (long)2 * D_STATE * M_ROWS;   // 32x1024 fp32

    dim3 blk(256);
    dim3 wblk(64);

    hipLaunchKernelGGL(split_kernel, dim3((M_ROWS * D_MODEL) / 1024), blk, 0, stream,
                       x, x_h, x_l, M_ROWS * D_MODEL);
    hipLaunchKernelGGL(split_kernel, dim3((N_XZ * D_MODEL) / 1024), blk, 0, stream,
                       W_in, w1_h, w1_l, N_XZ * D_MODEL);
    // 1) xz = x @ W_in^T   (M=1024, N=3072, K=768) — 768 wave-blocks
    hipLaunchKernelGGL((gemm_mfma<0>), dim3(N_XZ / 64, M_ROWS / 64), wblk, 0, stream,
                       x_h, x_l, D_MODEL, w1_h, w1_l, D_MODEL,
                       xz, N_XZ, (ushort_t*)nullptr, (ushort_t*)nullptr,
                       (float*)nullptr, (const float*)nullptr, N_XZ, D_MODEL);
    hipLaunchKernelGGL(split_kernel, dim3((D_INNER * D_INNER) / 1024), blk, 0, stream,
                       W_dt, w1_h, w1_l, D_INNER * D_INNER);
    // 2) conv + silu
    hipLaunchKernelGGL(conv_silu_kernel, dim3((M_ROWS * D_INNER) / 256), blk, 0, stream,
                       xz, conv_w, conv_b, xconvT, zsiluT, xc_h, xc_l);
    hipLaunchKernelGGL(split_kernel, dim3((N_XDBL * D_INNER) / 1024), blk, 0, stream,
                       W_x, w2_h, w2_l, N_XDBL * D_INNER);
    // 3) x_dbl = xconv @ W_x^T  (M=1024, N=1568, K=1536) — 400 wave-blocks
    hipLaunchKernelGGL((gemm_mfma<2>), dim3((N_XDBL + 63) / 64, M_ROWS / 64), wblk, 0, stream,
                       xc_h, xc_l, D_INNER, w2_h, w2_l, D_INNER,
                       x_dbl, N_XDBL, xd_h, xd_l,
                       BCT, (const float*)nullptr, N_XDBL, D_INNER);
    hipLaunchKernelGGL(split_kernel, dim3((D_MODEL * D_INNER) / 1024), blk, 0, stream,
                       W_out, w2_h, w2_l, D_MODEL * D_INNER);
    // 4) deltaT = softplus(W_dt @ x_dbl^T + b_dt)  (M=1536, N=1024, K=1536) — 384 blocks
    hipLaunchKernelGGL((gemm_mfma<1>), dim3(M_ROWS / 64, D_INNER / 64), wblk, 0, stream,
                       w1_h, w1_l, D_INNER, xd_h, xd_l, N_XDBL,
                       deltaT, M_ROWS, (ushort_t*)nullptr, (ushort_t*)nullptr,
                       (float*)nullptr, b_dt, M_ROWS, D_INNER);
    // 5) scan -> uT
    hipLaunchKernelGGL(scan_kernel, dim3(BATCH * (D_INNER / 4)), blk, 0, stream,
                       deltaT, xconvT, zsiluT, BCT, A_log, Dp, uT);
    // 5b) transpose+split uT -> u hi/lo
    hipLaunchKernelGGL(transpose_split_kernel, dim3(M_ROWS / 64, D_INNER / 64), blk, 0, stream,
                       uT, u_h, u_l);
    // 6) out = u @ W_out^T  (M=1024, N=768, K=1536) — 192 blocks
    hipLaunchKernelGGL((gemm_mfma<0>), dim3(D_MODEL / 64, M_ROWS / 64), wblk, 0, stream,
                       u_h, u_l, D_INNER, w2_h, w2_l, D_INNER,
                       out, D_MODEL, (ushort_t*)nullptr, (ushort_t*)nullptr,
                       (float*)nullptr, (const float*)nullptr, D_MODEL, D_INNER);
}